// Round 8
// baseline (305.305 us; speedup 1.0000x reference)
//
#include <hip/hip_runtime.h>

// Per-a batched GEMM, each H element fetched exactly once:
//   Yre[b,k] = sum_j Xre[b,j]*hr1[a,j,k] + Xim[b,j]*hi1[a,j,k]
//   Yim[b,k] = sum_j Xre[b,j]*hi2[a,j,k] + Xim[b,j]*hr2[a,j,k]
//
// Round-8: TLP redesign. History: ring-8/ILP variants (r4-r7) all spilled
// (WRITE_SIZE 99-204 MB vs 21 MB real output; allocator lands at 64 VGPR
// regardless of the 128 cap) and ran 83-104us; ring-4 r3 ran 57us at 16/32
// waves/CU. This round designs TO the 64-reg envelope and doubles occupancy:
//   Block = one 'a', 512 threads = 8 waves: wave = (ch, m, jh)
//     ch = output channel, m = matrix of pair (x channel c==m),
//     jh = j-half [0,64) / [64,128).
//   Lane: bh = lane>>5 (b half), kg = lane&31 -> k0 = 4*kg.
//   acc = 8 b x 4 k = 32 VGPR; H ring-2 = 8 VGPR; live ~56 <= 64.
//   __launch_bounds__(512, 8): VGPR cap 512/8 = 64 -> 32 waves/CU (100%).
//   Each (ch,m,jh) wave reads its 64 H rows exactly once (bh halves read
//   identical addresses -> one coalesced 512B request).
// Epilogue: 3-phase LDS tree reduce over (jh, m); 32 KB LDS (x-stage reused).
// Staging conflict-free: col = c*16+b spans 32 banks (verified 0 conflicts).

__global__ __launch_bounds__(512, 8)
void hmat_kernel(const float* __restrict__ x,
                 const float* __restrict__ hr1,
                 const float* __restrict__ hi1,
                 const float* __restrict__ hr2,
                 const float* __restrict__ hi2,
                 const int* __restrict__ perm,
                 float* __restrict__ out) {
  // [0,4096): x stage [j=128][col=c*16+b]; whole buffer: 4 reduce tiles
  // tile p = ch*2+m, 2048 floats each (16 b x 128 k).
  __shared__ float lds[8192];
  const int a = blockIdx.x;
  const int t = threadIdx.x;

  const int w    = t >> 6;      // wave 0..7
  const int ch   = w >> 2;      // output channel
  const int m    = (w >> 1) & 1;// matrix of the pair; x channel c == m
  const int jh   = w & 1;       // j half
  const int lane = t & 63;
  const int bh   = lane >> 5;   // b half: 0 -> b0..7, 1 -> b8..15
  const int kg   = lane & 31;
  const int k0   = kg * 4;

  const float* __restrict__ Hm =
      (ch == 0) ? (m == 0 ? hr1 : hi1) : (m == 0 ? hi2 : hr2);
  const float* __restrict__ hp = Hm + (size_t)a * 16384 + k0;
  const int jofs = jh * 64;

  // ---- stage permuted x into LDS (512 threads x 8 floats) ----
  // fields: c = t&1, b = (t>>1)&15, q = t>>5: jg = q>>2, seg = q&3.
  // col = c*16+b covers all 32 banks within each 32-lane group (2 lanes/bank
  // at different rows = free).
  {
    const int c   = t & 1;
    const int b   = (t >> 1) & 15;
    const int q   = t >> 5;
    const int jg  = q >> 2;
    const int seg = q & 3;
    const int row = perm[a * 4 + jg];
    const float4* src =
        (const float4*)(x + ((size_t)(b * 2 + c) * 4096 + (size_t)row) * 32 +
                        seg * 8);
    const float4 v0 = src[0];
    const float4 v1 = src[1];
    const int col = c * 16 + b;
    const int jb  = jg * 32 + seg * 8;
#define PUTX(V, Q)                            \
  lds[(jb + (Q)*4 + 0) * 32 + col] = (V).x;   \
  lds[(jb + (Q)*4 + 1) * 32 + col] = (V).y;   \
  lds[(jb + (Q)*4 + 2) * 32 + col] = (V).z;   \
  lds[(jb + (Q)*4 + 3) * 32 + col] = (V).w;
    PUTX(v0, 0) PUTX(v1, 1)
#undef PUTX
  }

  __syncthreads();

  const float* __restrict__ xp = lds + m * 16 + bh * 8;  // + J*32

  float4 acc[8];
#pragma unroll
  for (int i = 0; i < 8; ++i) acc[i] = make_float4(0.f, 0.f, 0.f, 0.f);

#define CONSUME(PF, J)                                                 \
  {                                                                    \
    const float4 xa = *(const float4*)(xp + (J) * 32);                 \
    const float4 xb = *(const float4*)(xp + (J) * 32 + 4);             \
    const float xs[8] = {xa.x, xa.y, xa.z, xa.w,                       \
                         xb.x, xb.y, xb.z, xb.w};                      \
    _Pragma("unroll") for (int bb = 0; bb < 8; ++bb) {                 \
      acc[bb].x = fmaf(xs[bb], (PF).x, acc[bb].x);                     \
      acc[bb].y = fmaf(xs[bb], (PF).y, acc[bb].y);                     \
      acc[bb].z = fmaf(xs[bb], (PF).z, acc[bb].z);                     \
      acc[bb].w = fmaf(xs[bb], (PF).w, acc[bb].w);                     \
    }                                                                  \
  }

  // ring-2 H prefetch (8 VGPR) — TLP (32 waves/CU) does the latency hiding.
  float4 pf0 = *(const float4*)(hp + (size_t)(jofs + 0) * 128);
  float4 pf1 = *(const float4*)(hp + (size_t)(jofs + 1) * 128);

  for (int j = 0; j < 62; j += 2) {
    CONSUME(pf0, jofs + j);
    pf0 = *(const float4*)(hp + (size_t)(jofs + j + 2) * 128);
    CONSUME(pf1, jofs + j + 1);
    pf1 = *(const float4*)(hp + (size_t)(jofs + j + 3) * 128);
  }
  CONSUME(pf0, jofs + 62);
  CONSUME(pf1, jofs + 63);
#undef CONSUME

  // ---- 3-phase LDS tree reduce over (jh, m) ----
  __syncthreads();  // everyone done reading the x stage

  const int tile = (ch * 2 + m) * 2048;
  // phase 1: jh==1 waves dump partials
  if (jh == 1) {
#pragma unroll
    for (int bb = 0; bb < 8; ++bb)
      *(float4*)&lds[tile + (bh * 8 + bb) * 128 + k0] = acc[bb];
  }
  __syncthreads();
  // phase 2: jh==0 waves fold their j-half partner; m==1 re-dump
  if (jh == 0) {
#pragma unroll
    for (int bb = 0; bb < 8; ++bb) {
      const float4 o = *(const float4*)&lds[tile + (bh * 8 + bb) * 128 + k0];
      acc[bb].x += o.x;
      acc[bb].y += o.y;
      acc[bb].z += o.z;
      acc[bb].w += o.w;
    }
  }
  __syncthreads();
  if (jh == 0 && m == 1) {
#pragma unroll
    for (int bb = 0; bb < 8; ++bb)
      *(float4*)&lds[tile + (bh * 8 + bb) * 128 + k0] = acc[bb];
  }
  __syncthreads();
  // phase 3: (jh==0, m==0) waves fold the m partner and store
  if (jh == 0 && m == 0) {
#pragma unroll
    for (int bb = 0; bb < 8; ++bb) {
      const float4 o =
          *(const float4*)&lds[(ch * 2 + 1) * 2048 + (bh * 8 + bb) * 128 + k0];
      const int b = bh * 8 + bb;
      float4 r;
      r.x = acc[bb].x + o.x;
      r.y = acc[bb].y + o.y;
      r.z = acc[bb].z + o.z;
      r.w = acc[bb].w + o.w;
      *(float4*)(out + (size_t)(b * 2 + ch) * 131072 + (size_t)a * 128 + k0) =
          r;
    }
  }
}

extern "C" void kernel_launch(void* const* d_in, const int* in_sizes, int n_in,
                              void* d_out, int out_size, void* d_ws, size_t ws_size,
                              hipStream_t stream) {
  const float* x   = (const float*)d_in[0];
  const float* hr1 = (const float*)d_in[1];
  const float* hi1 = (const float*)d_in[2];
  const float* hr2 = (const float*)d_in[3];
  const float* hi2 = (const float*)d_in[4];
  const int* perm  = (const int*)d_in[5];
  float* out = (float*)d_out;

  hipLaunchKernelGGL(hmat_kernel, dim3(1024), dim3(512), 0, stream,
                     x, hr1, hi1, hr2, hi2, perm, out);
}

// Round 9
// 135.567 us; speedup vs baseline: 2.2521x; 2.2521x over previous
//
#include <hip/hip_runtime.h>

// Per-a batched GEMM, each H element fetched exactly once:
//   Yre[b,k] = sum_j Xre[b,j]*hr1[a,j,k] + Xim[b,j]*hi1[a,j,k]
//   Yim[b,k] = sum_j Xre[b,j]*hi2[a,j,k] + Xim[b,j]*hr2[a,j,k]
//
// Round-9: r3 skeleton (the only WRITE-clean fast variant, 57us) with the
// register H-ring replaced by a wave-private 6-slot LDS ring filled via
// __builtin_amdgcn_global_load_lds (async DMA, no VGPR round-trip) and
// counted s_waitcnt vmcnt(5) — never drained to 0 in the loop (T3/T4).
// Rationale: r4-r8 all proved the allocator spills any VGPR-funded pipeline
// deeper than r3's (WRITE_SIZE 99-720 MB of scratch); LDS funds the depth
// instead. Wave-private ring => no barriers in the K-loop.
//   Block = one 'a', 256 threads = 4 waves: wave = (ch, jh).
//   Lane: m = lane>>5 (matrix of pair, x channel c==m), kg = lane&31.
//   acc = 16 b x 4 k = 64 VGPR (r3-proven); h = 4 VGPR (was 16-reg ring).
//   DMA slot = 1 KB = one j-row of both matrices; dest = uniform base +
//   lane*16 == lane's (m,kg) 16B slice; lane ds_reads back its own bytes.
// LDS: [0,4096) x-stage [j][c*16+b] (r6's 0-conflict staging) reused as
// reduce buf; [4096,10240) = 4 waves x 6 slots x 256 floats. 40 KB/block.

typedef unsigned int u32;
__device__ __forceinline__ void gld_lds16(const float* g, float* l) {
  __builtin_amdgcn_global_load_lds(
      (const __attribute__((address_space(1))) u32*)g,
      (__attribute__((address_space(3))) u32*)l, 16, 0, 0);
}

__global__ __launch_bounds__(256, 4)
void hmat_kernel(const float* __restrict__ x,
                 const float* __restrict__ hr1,
                 const float* __restrict__ hi1,
                 const float* __restrict__ hr2,
                 const float* __restrict__ hi2,
                 const int* __restrict__ perm,
                 float* __restrict__ out) {
  __shared__ float lds[10240];
  const int a = blockIdx.x;
  const int t = threadIdx.x;

  const int w    = t >> 6;     // wave 0..3
  const int ch   = w >> 1;     // output channel
  const int jh   = w & 1;      // j half
  const int lane = t & 63;
  const int m    = lane >> 5;  // matrix of pair; x channel c == m
  const int kg   = lane & 31;
  const int k0   = kg * 4;

  const float* __restrict__ Hm =
      (ch == 0) ? (m == 0 ? hr1 : hi1) : (m == 0 ? hi2 : hr2);
  const float* __restrict__ hsrc = Hm + (size_t)a * 16384 + k0;  // + row*128
  const int jofs = jh * 64;

  // ---- stage permuted x into LDS (r6's verified 0-conflict pattern) ----
  {
    const int c    = t & 1;
    const int b    = (t >> 1) & 15;
    const int q    = t >> 5;
    const int jg   = q >> 1;
    const int half = q & 1;
    const int row  = perm[a * 4 + jg];
    const float4* src =
        (const float4*)(x + ((size_t)(b * 2 + c) * 4096 + (size_t)row) * 32 +
                        half * 16);
    float4 v0 = src[0], v1 = src[1], v2 = src[2], v3 = src[3];
    const int col = c * 16 + b;
    const int jb  = jg * 32 + half * 16;
#define PUTX(V, Q)                            \
  lds[(jb + (Q)*4 + 0) * 32 + col] = (V).x;   \
  lds[(jb + (Q)*4 + 1) * 32 + col] = (V).y;   \
  lds[(jb + (Q)*4 + 2) * 32 + col] = (V).z;   \
  lds[(jb + (Q)*4 + 3) * 32 + col] = (V).w;
    PUTX(v0, 0) PUTX(v1, 1) PUTX(v2, 2) PUTX(v3, 3)
#undef PUTX
  }

  __syncthreads();

  float* __restrict__ ring = &lds[4096 + w * 1536];  // 6 slots x 256 floats

  // prologue: fill the 6-slot ring (vmcnt -> 6 outstanding)
#pragma unroll
  for (int d = 0; d < 6; ++d)
    gld_lds16(hsrc + (size_t)(jofs + d) * 128, ring + d * 256);

  const float* __restrict__ xp = lds + m * 16;  // + J*32

  float4 acc[16];
#pragma unroll
  for (int i = 0; i < 16; ++i) acc[i] = make_float4(0.f, 0.f, 0.f, 0.f);

  // One step: wait oldest DMA (vmcnt 6 -> 5), consume slot S, refill slot S
  // with row i+6 (clamped; clamped refills land in already-read slots only).
  // Refill sits after the fmas + lgkmcnt(0) so the slot's ds_read has
  // completed before the DMA can overwrite it.
#define STEP(IB, S)                                                        \
  {                                                                        \
    const int i = (IB) + (S);                                              \
    asm volatile("s_waitcnt vmcnt(5)" ::: "memory");                       \
    __builtin_amdgcn_sched_barrier(0);                                     \
    const float4 h = *(const float4*)(ring + (S) * 256 + lane * 4);        \
    const float* xj = xp + (size_t)(jofs + i) * 32;                        \
    const float4 xa = *(const float4*)(xj + 0);                            \
    const float4 xb = *(const float4*)(xj + 4);                            \
    const float4 xc = *(const float4*)(xj + 8);                            \
    const float4 xd = *(const float4*)(xj + 12);                           \
    const float xs[16] = {xa.x, xa.y, xa.z, xa.w, xb.x, xb.y, xb.z, xb.w,  \
                          xc.x, xc.y, xc.z, xc.w, xd.x, xd.y, xd.z, xd.w}; \
    _Pragma("unroll") for (int bb = 0; bb < 16; ++bb) {                    \
      acc[bb].x = fmaf(xs[bb], h.x, acc[bb].x);                            \
      acc[bb].y = fmaf(xs[bb], h.y, acc[bb].y);                            \
      acc[bb].z = fmaf(xs[bb], h.z, acc[bb].z);                            \
      acc[bb].w = fmaf(xs[bb], h.w, acc[bb].w);                            \
    }                                                                      \
    __builtin_amdgcn_sched_barrier(0);                                     \
    asm volatile("s_waitcnt lgkmcnt(0)" ::: "memory");                     \
    const int nr = (i + 6 > 63) ? 63 : (i + 6);                            \
    gld_lds16(hsrc + (size_t)(jofs + nr) * 128, ring + (S) * 256);         \
  }

  for (int ii = 0; ii < 60; ii += 6) {
    STEP(ii, 0) STEP(ii, 1) STEP(ii, 2)
    STEP(ii, 3) STEP(ii, 4) STEP(ii, 5)
  }
  STEP(60, 0) STEP(60, 1) STEP(60, 2) STEP(60, 3)
#undef STEP

  // ---- fold the two matrix-halves: lane p += lane p^32 ----
#pragma unroll
  for (int bb = 0; bb < 16; ++bb) {
    acc[bb].x += __shfl_xor(acc[bb].x, 32, 64);
    acc[bb].y += __shfl_xor(acc[bb].y, 32, 64);
    acc[bb].z += __shfl_xor(acc[bb].z, 32, 64);
    acc[bb].w += __shfl_xor(acc[bb].w, 32, 64);
  }

  // ---- reduce the two j-halves via LDS (reuse x-stage region) ----
  __syncthreads();  // also drains the residual ring DMAs (vmcnt 0)
  if (jh == 1 && m == 0) {
#pragma unroll
    for (int bb = 0; bb < 16; ++bb)
      *(float4*)&lds[ch * 2048 + bb * 128 + k0] = acc[bb];
  }
  __syncthreads();
  if (jh == 0 && m == 0) {
#pragma unroll
    for (int bb = 0; bb < 16; ++bb) {
      const float4 o = *(const float4*)&lds[ch * 2048 + bb * 128 + k0];
      float4 r;
      r.x = acc[bb].x + o.x;
      r.y = acc[bb].y + o.y;
      r.z = acc[bb].z + o.z;
      r.w = acc[bb].w + o.w;
      *(float4*)(out + (size_t)(bb * 2 + ch) * 131072 + (size_t)a * 128 + k0) =
          r;
    }
  }
}

extern "C" void kernel_launch(void* const* d_in, const int* in_sizes, int n_in,
                              void* d_out, int out_size, void* d_ws, size_t ws_size,
                              hipStream_t stream) {
  const float* x   = (const float*)d_in[0];
  const float* hr1 = (const float*)d_in[1];
  const float* hi1 = (const float*)d_in[2];
  const float* hr2 = (const float*)d_in[3];
  const float* hi2 = (const float*)d_in[4];
  const int* perm  = (const int*)d_in[5];
  float* out = (float*)d_out;

  hipLaunchKernelGGL(hmat_kernel, dim3(1024), dim3(256), 0, stream,
                     x, hr1, hi1, hr2, hi2, perm, out);
}

// Round 10
// 58.198 us; speedup vs baseline: 5.2460x; 2.3294x over previous
//
#include <hip/hip_runtime.h>

// Per-a batched GEMM, each H element fetched exactly once:
//   Yre[b,k] = sum_j Xre[b,j]*hr1[a,j,k] + Xim[b,j]*hi1[a,j,k]
//   Yim[b,k] = sum_j Xre[b,j]*hi2[a,j,k] + Xim[b,j]*hr2[a,j,k]
//
// Round-10: TLP within the r3 shape (the only WRITE-clean fast variant).
// Session evidence: every pipeline deeper than r3's envelope spilled
// (WRITE_SIZE 99-720 MB, r4-r9); r3 itself is latency-bound at 16 waves/CU
// with all pipes <30%. This round doubles the block count instead:
//   grid 2048 = (a, kh): block covers k in [kh*64, kh*64+64). Outputs are
//   k-disjoint (no cross-block reduce); H traffic still exactly-once;
//   only the 16 KB x stage duplicates (+16 MB, L3-served).
//   Block = 256 threads = 4 waves (ch, jh) -- r3's wave map.
//   Lane = (m = lane>>5, bh = (lane>>4)&1, kg = lane&15):
//     acc = 8 b x 4 k = 32 VGPR (half of r3 -> nominal live ~70, inside the
//     proven-clean envelope). Ring-4 immediate-consume H prefetch (r3's).
//   H load: per m-half, 16 float4 x 2 lanes = 256 B contiguous, coalesced.
// Staging: r6's verified 0-conflict pattern. launch_bounds(256,4) -- never
// force a tighter cap (r8: forced caps make the allocator spill).

__global__ __launch_bounds__(256, 4)
void hmat_kernel(const float* __restrict__ x,
                 const float* __restrict__ hr1,
                 const float* __restrict__ hi1,
                 const float* __restrict__ hr2,
                 const float* __restrict__ hi2,
                 const int* __restrict__ perm,
                 float* __restrict__ out) {
  __shared__ float lds[4096];  // x stage [j=128][col=c*16+b]; then reduce buf
  const int bid = blockIdx.x;
  const int a   = bid >> 1;
  const int kh  = bid & 1;
  const int t   = threadIdx.x;

  const int w    = t >> 6;          // wave 0..3
  const int ch   = w >> 1;          // output channel
  const int jh   = w & 1;           // j half
  const int lane = t & 63;
  const int m    = lane >> 5;       // matrix of pair; x channel c == m
  const int bh   = (lane >> 4) & 1; // b half: 8 b each
  const int kg   = lane & 15;       // k group of 4 within this block's 64 k
  const int k0   = kh * 64 + kg * 4;
  const int b0   = bh * 8;

  const float* __restrict__ Hm =
      (ch == 0) ? (m == 0 ? hr1 : hi1) : (m == 0 ? hi2 : hr2);
  const float* __restrict__ hp = Hm + (size_t)a * 16384 + k0;
  const int jofs = jh * 64;

  // ---- stage permuted x into LDS (r6's verified 0-conflict pattern) ----
  {
    const int c    = t & 1;
    const int b    = (t >> 1) & 15;
    const int q    = t >> 5;
    const int jg   = q >> 1;
    const int half = q & 1;
    const int row  = perm[a * 4 + jg];
    const float4* src =
        (const float4*)(x + ((size_t)(b * 2 + c) * 4096 + (size_t)row) * 32 +
                        half * 16);
    float4 v0 = src[0], v1 = src[1], v2 = src[2], v3 = src[3];
    const int col = c * 16 + b;
    const int jb  = jg * 32 + half * 16;
#define PUTX(V, Q)                            \
  lds[(jb + (Q)*4 + 0) * 32 + col] = (V).x;   \
  lds[(jb + (Q)*4 + 1) * 32 + col] = (V).y;   \
  lds[(jb + (Q)*4 + 2) * 32 + col] = (V).z;   \
  lds[(jb + (Q)*4 + 3) * 32 + col] = (V).w;
    PUTX(v0, 0) PUTX(v1, 1) PUTX(v2, 2) PUTX(v3, 3)
#undef PUTX
  }

  __syncthreads();

  // ring-4 H prefetch, r3's immediate-consume pattern
  float4 pf0 = *(const float4*)(hp + (size_t)(jofs + 0) * 128);
  float4 pf1 = *(const float4*)(hp + (size_t)(jofs + 1) * 128);
  float4 pf2 = *(const float4*)(hp + (size_t)(jofs + 2) * 128);
  float4 pf3 = *(const float4*)(hp + (size_t)(jofs + 3) * 128);

  const float* __restrict__ xp = lds + m * 16 + b0;  // + J*32

  float4 acc[8];
#pragma unroll
  for (int i = 0; i < 8; ++i) acc[i] = make_float4(0.f, 0.f, 0.f, 0.f);

#define CONSUME(PF, J)                                                 \
  {                                                                    \
    const float4 xa = *(const float4*)(xp + (J) * 32);                 \
    const float4 xb = *(const float4*)(xp + (J) * 32 + 4);             \
    const float xs[8] = {xa.x, xa.y, xa.z, xa.w,                       \
                         xb.x, xb.y, xb.z, xb.w};                      \
    _Pragma("unroll") for (int bb = 0; bb < 8; ++bb) {                 \
      acc[bb].x = fmaf(xs[bb], (PF).x, acc[bb].x);                     \
      acc[bb].y = fmaf(xs[bb], (PF).y, acc[bb].y);                     \
      acc[bb].z = fmaf(xs[bb], (PF).z, acc[bb].z);                     \
      acc[bb].w = fmaf(xs[bb], (PF).w, acc[bb].w);                     \
    }                                                                  \
  }

  for (int j4 = 0; j4 < 60; j4 += 4) {
    CONSUME(pf0, jofs + j4 + 0)
    pf0 = *(const float4*)(hp + (size_t)(jofs + j4 + 4) * 128);
    CONSUME(pf1, jofs + j4 + 1)
    pf1 = *(const float4*)(hp + (size_t)(jofs + j4 + 5) * 128);
    CONSUME(pf2, jofs + j4 + 2)
    pf2 = *(const float4*)(hp + (size_t)(jofs + j4 + 6) * 128);
    CONSUME(pf3, jofs + j4 + 3)
    pf3 = *(const float4*)(hp + (size_t)(jofs + j4 + 7) * 128);
  }
  CONSUME(pf0, jofs + 60)
  CONSUME(pf1, jofs + 61)
  CONSUME(pf2, jofs + 62)
  CONSUME(pf3, jofs + 63)
#undef CONSUME

  // ---- fold the two matrix-halves: lane p += lane p^32 ----
#pragma unroll
  for (int bb = 0; bb < 8; ++bb) {
    acc[bb].x += __shfl_xor(acc[bb].x, 32, 64);
    acc[bb].y += __shfl_xor(acc[bb].y, 32, 64);
    acc[bb].z += __shfl_xor(acc[bb].z, 32, 64);
    acc[bb].w += __shfl_xor(acc[bb].w, 32, 64);
  }

  // ---- reduce the two j-halves via LDS (reuse x-stage region) ----
  // buf: [ch][b=16][kg*4 .. +4) -> 2*16*64 = 2048 floats
  __syncthreads();  // all waves done reading the x stage
  if (jh == 1 && m == 0) {
#pragma unroll
    for (int bb = 0; bb < 8; ++bb)
      *(float4*)&lds[ch * 1024 + (b0 + bb) * 64 + kg * 4] = acc[bb];
  }
  __syncthreads();
  if (jh == 0 && m == 0) {
#pragma unroll
    for (int bb = 0; bb < 8; ++bb) {
      const float4 o = *(const float4*)&lds[ch * 1024 + (b0 + bb) * 64 + kg * 4];
      const int b = b0 + bb;
      float4 r;
      r.x = acc[bb].x + o.x;
      r.y = acc[bb].y + o.y;
      r.z = acc[bb].z + o.z;
      r.w = acc[bb].w + o.w;
      *(float4*)(out + (size_t)(b * 2 + ch) * 131072 + (size_t)a * 128 + k0) =
          r;
    }
  }
}

extern "C" void kernel_launch(void* const* d_in, const int* in_sizes, int n_in,
                              void* d_out, int out_size, void* d_ws, size_t ws_size,
                              hipStream_t stream) {
  const float* x   = (const float*)d_in[0];
  const float* hr1 = (const float*)d_in[1];
  const float* hi1 = (const float*)d_in[2];
  const float* hr2 = (const float*)d_in[3];
  const float* hi2 = (const float*)d_in[4];
  const int* perm  = (const int*)d_in[5];
  float* out = (float*)d_out;

  hipLaunchKernelGGL(hmat_kernel, dim3(2048), dim3(256), 0, stream,
                     x, hr1, hi1, hr2, hi2, perm, out);
}